// Round 2
// baseline (871.179 us; speedup 1.0000x reference)
//
#include <hip/hip_runtime.h>
#include <hip/hip_bf16.h>
#include <stdint.h>

// out[b,s,n] = sum_k nvfp4_fq(x)[b,s,k] * nvfp4_fq(W)[n,k] + bias[n]
// M=8192 (4*2048), N=4096, K=4096.
//
// Exactness: xq = q4 * (sc8/gscale); q4 (fp4-e2m1) has <=2-bit significand,
// sc8 (fp8-e4m3) <=4-bit -> q4*sc8 has <=5-bit significand -> EXACT in bf16.
//   out = [ sum_k (q4x*sc8x)*(q4w*sc8w) ] / (gsx*gsw) + bias
// via bf16 MFMA with fp32 accumulation == reference fp32 math (mod sum order,
// and one deferred global-scale multiply instead of two per-element ones).

#define GM 8192
#define GN 4096
#define GK 4096

#define BM 128
#define BN 128
#define BK 64

typedef short bf16x8 __attribute__((ext_vector_type(8)));  // env-verified frag type (guide §3)
typedef float f32x4 __attribute__((ext_vector_type(4)));

// Matches reference _round_to_fp: e = max(floor(log2(a)), min_exp),
// step = 2^(e-mant_bits), q = min(rint(a/step)*step, max_val), signed.
// Exponent by bit-extract == floor(log2) for normal a; fp32 rounding of log2
// at 2^k boundaries is benign (adjacent-exponent grids agree at 2^k).
__device__ __forceinline__ float round_tiny(float x, int mant_bits, int min_exp, float max_val) {
  float a = fabsf(x);
  if (a == 0.0f) return 0.0f;
  int e = (int)((__float_as_uint(a) >> 23) & 0xFFu) - 127;
  if (e < min_exp) e = min_exp;
  float step = __int_as_float((unsigned)(e - mant_bits + 127) << 23);  // 2^(e-mant)
  float q = fminf(rintf(a / step) * step, max_val);  // rintf = RNE = jnp.round
  return copysignf(q, x);
}

__global__ void amax_kernel(const float4* __restrict__ src, int n4, unsigned int* __restrict__ out) {
  float m = 0.0f;
  int stride = gridDim.x * blockDim.x;
  for (int i = blockIdx.x * blockDim.x + threadIdx.x; i < n4; i += stride) {
    float4 v = src[i];
    m = fmaxf(m, fmaxf(fmaxf(fabsf(v.x), fabsf(v.y)), fmaxf(fabsf(v.z), fabsf(v.w))));
  }
#pragma unroll
  for (int off = 32; off > 0; off >>= 1) m = fmaxf(m, __shfl_xor(m, off, 64));
  if ((threadIdx.x & 63) == 0) atomicMax(out, __float_as_uint(m));  // |x|>=0: uint cmp == float cmp
}

// One thread per 16-elem nvfp4 block (blocks never straddle rows: K%16==0).
__global__ void quant_kernel(const float* __restrict__ src, unsigned short* __restrict__ dst,
                             const unsigned int* __restrict__ amax_bits, int nblk) {
  const float amax = __uint_as_float(amax_bits[0]);
  const float gscale = 2688.0f / amax;  // 448*6/amax, same op order as reference
  int stride = gridDim.x * blockDim.x;
  for (int i = blockIdx.x * blockDim.x + threadIdx.x; i < nblk; i += stride) {
    const float4* p = (const float4*)src + (size_t)i * 4;
    float4 v0 = p[0], v1 = p[1], v2 = p[2], v3 = p[3];
    float vals[16] = {v0.x, v0.y, v0.z, v0.w, v1.x, v1.y, v1.z, v1.w,
                      v2.x, v2.y, v2.z, v2.w, v3.x, v3.y, v3.z, v3.w};
    float bmax = 0.0f;
#pragma unroll
    for (int j = 0; j < 16; ++j) bmax = fmaxf(bmax, fabsf(vals[j]));
    float sc8 = round_tiny(bmax / 6.0f * gscale, 3, -6, 448.0f);  // fp8-e4m3 block scale
    unsigned short o[16];
    if (sc8 > 0.0f) {
      float sc = sc8 / gscale;  // same fp32 division as reference's sc
#pragma unroll
      for (int j = 0; j < 16; ++j) {
        float q = round_tiny(vals[j] / sc, 1, 0, 6.0f);  // fp4-e2m1 value
        float d = q * sc8;                               // exact, <=5-bit significand
        unsigned u = __float_as_uint(d);
        u += 0x7FFFu + ((u >> 16) & 1u);                 // RNE to bf16 (exact here)
        o[j] = (unsigned short)(u >> 16);
      }
    } else {
#pragma unroll
      for (int j = 0; j < 16; ++j) o[j] = 0;
    }
    uint4* dq = (uint4*)(dst + (size_t)i * 16);
    const uint4* oq = (const uint4*)o;
    dq[0] = oq[0];
    dq[1] = oq[1];
  }
}

// m97-structure GEMM: 128x128 tile, BK=64, 4 waves (2x2 of 64x64),
// global_load_lds width-16 staging, XOR-swizzled LDS (linear dest +
// inverse-swizzled global source + swizzled ds_read — rule #21),
// XCD-aware block swizzle (T1; nwg=2048, %8==0 -> simple form bijective).
__global__ __launch_bounds__(256) void gemm_bt(
    const unsigned short* __restrict__ A,   // [GM][GK] bf16 bits = q4x*sc8x
    const unsigned short* __restrict__ Bt,  // [GN][GK] bf16 bits = q4w*sc8w
    const float* __restrict__ bias,
    const unsigned int* __restrict__ amax2,
    float* __restrict__ C) {
  __shared__ unsigned short As[BM * BK];  // 16 KiB, 128 B per row
  __shared__ unsigned short Bs[BN * BK];  // 16 KiB
  const int tid  = threadIdx.x;
  const int lane = tid & 63;
  const int wave = tid >> 6;

  // XCD swizzle: consecutive tiles per XCD share A row-panels.
  const int nwg = gridDim.x * gridDim.y;            // 2048
  const int id  = blockIdx.y * gridDim.x + blockIdx.x;
  const int swz = (id & 7) * (nwg >> 3) + (id >> 3);
  const int brow = (swz / gridDim.x) * BM;
  const int bcol = (swz % gridDim.x) * BN;

  const int wr = (wave >> 1) * 64;
  const int wc = (wave & 1) * 64;

  f32x4 acc[4][4] = {};

  // Staging: 4 rounds x (4 waves x 64 lanes x 16B) = 16 KiB per tile.
  // Linear LDS offset L -> (row, cb); fetch global from cb ^ ((row&7)<<4)
  // so swizzled ds_reads see the right data (source and read use the same
  // involution; LDS dest stays linear as global_load_lds requires).
  int srow[4], scolb[4];
#pragma unroll
  for (int r = 0; r < 4; ++r) {
    int L = r * 4096 + wave * 1024 + lane * 16;
    int row = L >> 7;
    int cb  = L & 127;
    srow[r]  = row;
    scolb[r] = cb ^ ((row & 7) << 4);
  }

  for (int kt = 0; kt < GK; kt += BK) {
#pragma unroll
    for (int r = 0; r < 4; ++r) {
      const char* sa = (const char*)A  + (((size_t)(brow + srow[r]) * GK + kt) * 2 + scolb[r]);
      const char* sb = (const char*)Bt + (((size_t)(bcol + srow[r]) * GK + kt) * 2 + scolb[r]);
      __builtin_amdgcn_global_load_lds(
          (__attribute__((address_space(1))) void*)sa,
          (__attribute__((address_space(3))) void*)((char*)As + r * 4096 + wave * 1024),
          16, 0, 0);
      __builtin_amdgcn_global_load_lds(
          (__attribute__((address_space(1))) void*)sb,
          (__attribute__((address_space(3))) void*)((char*)Bs + r * 4096 + wave * 1024),
          16, 0, 0);
    }
    __syncthreads();  // compiler drains vmcnt before barrier
#pragma unroll
    for (int kk = 0; kk < 2; ++kk) {
      bf16x8 af[4], bfv[4];
      // A frag (16x16x32): lane l holds A[row = l&15][k = (l>>4)*8 + j]
#pragma unroll
      for (int m = 0; m < 4; ++m) {
        int row = wr + m * 16 + (lane & 15);
        int cb  = kk * 64 + ((lane >> 4) << 4);
        af[m] = *(const bf16x8*)((const char*)As + row * 128 + (cb ^ ((row & 7) << 4)));
      }
#pragma unroll
      for (int n = 0; n < 4; ++n) {
        int row = wc + n * 16 + (lane & 15);
        int cb  = kk * 64 + ((lane >> 4) << 4);
        bfv[n] = *(const bf16x8*)((const char*)Bs + row * 128 + (cb ^ ((row & 7) << 4)));
      }
#pragma unroll
      for (int m = 0; m < 4; ++m)
#pragma unroll
        for (int n = 0; n < 4; ++n)
          acc[m][n] = __builtin_amdgcn_mfma_f32_16x16x32_bf16(af[m], bfv[n], acc[m][n], 0, 0, 0);
    }
    __syncthreads();
  }

  // Epilogue: C = acc / (gsx*gsw) + bias. C/D layout: col=lane&15, row=(lane>>4)*4+j.
  const float ax = __uint_as_float(amax2[0]);
  const float aw = __uint_as_float(amax2[1]);
  const float inv = 1.0f / ((2688.0f / ax) * (2688.0f / aw));
#pragma unroll
  for (int m = 0; m < 4; ++m) {
    int row0 = brow + wr + m * 16 + ((lane >> 4) << 2);
#pragma unroll
    for (int n = 0; n < 4; ++n) {
      int col = bcol + wc + n * 16 + (lane & 15);
      float bb = bias[col];
#pragma unroll
      for (int j = 0; j < 4; ++j)
        C[(size_t)(row0 + j) * GN + col] = acc[m][n][j] * inv + bb;
    }
  }
}

extern "C" void kernel_launch(void* const* d_in, const int* in_sizes, int n_in,
                              void* d_out, int out_size, void* d_ws, size_t ws_size,
                              hipStream_t stream) {
  const float* x = (const float*)d_in[0];  // 4*2048*4096 fp32
  const float* W = (const float*)d_in[1];  // 4096*4096 fp32
  const float* b = (const float*)d_in[2];  // 4096 fp32
  float* out = (float*)d_out;              // 8192*4096 fp32

  // ws layout: [0,8) amax bits (x, W); A' bf16 at +256 (64 MiB); B' after (32 MiB).
  // Requires ws_size >= ~100.7 MB.
  unsigned int* amax2 = (unsigned int*)d_ws;
  unsigned short* Aq = (unsigned short*)((char*)d_ws + 256);
  unsigned short* Bq = Aq + (size_t)GM * GK;

  hipMemsetAsync(d_ws, 0, 8, stream);  // amax accumulators start at 0 (ws is poisoned)
  amax_kernel<<<2048, 256, 0, stream>>>((const float4*)x, GM * GK / 4, amax2);
  amax_kernel<<<2048, 256, 0, stream>>>((const float4*)W, GN * GK / 4, amax2 + 1);
  quant_kernel<<<2048, 256, 0, stream>>>(x, Aq, amax2, GM * GK / 16);
  quant_kernel<<<2048, 256, 0, stream>>>(W, Bq, amax2 + 1, GN * GK / 16);
  dim3 grid(GN / BN, GM / BM);
  gemm_bt<<<grid, 256, 0, stream>>>(Aq, Bq, b, amax2, out);
}

// Round 3
// 529.577 us; speedup vs baseline: 1.6450x; 1.6450x over previous
//
#include <hip/hip_runtime.h>
#include <hip/hip_bf16.h>
#include <stdint.h>

// out[b,s,n] = sum_k nvfp4_fq(x)[b,s,k] * nvfp4_fq(W)[n,k] + bias[n]
// M=8192, N=4096, K=4096.
// Exactness: xq = q4*(sc8/gscale); q4 (e2m1) <=2-bit significand, sc8 (e4m3)
// <=4-bit -> product <=6-bit significand -> EXACT bf16. GEMM in bf16 MFMA
// (fp32 accum) == reference fp32 math modulo summation order; one deferred
// global scale 1/(gsx*gsw) in the epilogue.

#define GM 8192
#define GN 4096
#define GK 4096

#define BM 256
#define BN 256
#define BK 64
#define NT (GK / BK)  // 64 K-tiles; 4 half-stages per tile -> 256 halves

typedef short bf16x8 __attribute__((ext_vector_type(8)));
typedef float f32x4 __attribute__((ext_vector_type(4)));

// Reference _round_to_fp, bit-exact. a/step and *step replaced by exact
// power-of-2 multiplies (no rounding: pow2 mul is exact in range).
__device__ __forceinline__ float round_tiny(float x, int mant_bits, int min_exp, float max_val) {
  float a = fabsf(x);
  if (a == 0.0f) return 0.0f;
  int e = (int)((__float_as_uint(a) >> 23) & 0xFFu) - 127;
  if (e < min_exp) e = min_exp;
  float s_up = __int_as_float((unsigned)(mant_bits - e + 127) << 23);  // 2^(m-e)
  float s_dn = __int_as_float((unsigned)(e - mant_bits + 127) << 23);  // 2^(e-m)
  float q = fminf(rintf(a * s_up) * s_dn, max_val);  // == min(rint(a/step)*step, max)
  return copysignf(q, x);
}

// ---- amax: atomic-free two-stage (G12: same-address atomics serialized) ----
__global__ void amax_part(const float4* __restrict__ src, int n4, float* __restrict__ part) {
  float m = 0.0f;
  int stride = gridDim.x * blockDim.x;
  for (int i = blockIdx.x * blockDim.x + threadIdx.x; i < n4; i += stride) {
    float4 v = src[i];
    m = fmaxf(m, fmaxf(fmaxf(fabsf(v.x), fabsf(v.y)), fmaxf(fabsf(v.z), fabsf(v.w))));
  }
#pragma unroll
  for (int off = 32; off > 0; off >>= 1) m = fmaxf(m, __shfl_xor(m, off, 64));
  __shared__ float sm[4];
  int wave = threadIdx.x >> 6;
  if ((threadIdx.x & 63) == 0) sm[wave] = m;
  __syncthreads();
  if (threadIdx.x == 0)
    part[blockIdx.x] = fmaxf(fmaxf(sm[0], sm[1]), fmaxf(sm[2], sm[3]));
}

__global__ void amax_final(const float* __restrict__ px, const float* __restrict__ pw,
                           unsigned int* __restrict__ amax2) {
  int t = threadIdx.x;  // 512 threads
  float mx = fmaxf(px[t], px[t + 512]);  // 1024 x-partials
  float mw = pw[t];                      // 512 W-partials
#pragma unroll
  for (int off = 32; off > 0; off >>= 1) {
    mx = fmaxf(mx, __shfl_xor(mx, off, 64));
    mw = fmaxf(mw, __shfl_xor(mw, off, 64));
  }
  __shared__ float sx[8], sw[8];
  int wave = t >> 6;
  if ((t & 63) == 0) { sx[wave] = mx; sw[wave] = mw; }
  __syncthreads();
  if (t == 0) {
    float ax = sx[0], aw = sw[0];
#pragma unroll
    for (int i = 1; i < 8; ++i) { ax = fmaxf(ax, sx[i]); aw = fmaxf(aw, sw[i]); }
    amax2[0] = __float_as_uint(ax);
    amax2[1] = __float_as_uint(aw);
  }
}

// One thread per 16-elem nvfp4 block.
__global__ void quant_kernel(const float* __restrict__ src, unsigned short* __restrict__ dst,
                             const unsigned int* __restrict__ amax_bits, int nblk) {
  const float amax = __uint_as_float(amax_bits[0]);
  const float gscale = 2688.0f / amax;  // 448*6/amax
  int stride = gridDim.x * blockDim.x;
  for (int i = blockIdx.x * blockDim.x + threadIdx.x; i < nblk; i += stride) {
    const float4* p = (const float4*)src + (size_t)i * 4;
    float4 v0 = p[0], v1 = p[1], v2 = p[2], v3 = p[3];
    float vals[16] = {v0.x, v0.y, v0.z, v0.w, v1.x, v1.y, v1.z, v1.w,
                      v2.x, v2.y, v2.z, v2.w, v3.x, v3.y, v3.z, v3.w};
    float bmax = 0.0f;
#pragma unroll
    for (int j = 0; j < 16; ++j) bmax = fmaxf(bmax, fabsf(vals[j]));
    float sc8 = round_tiny(bmax / 6.0f * gscale, 3, -6, 448.0f);  // fp8-e4m3
    unsigned short o[16];
    if (sc8 > 0.0f) {
      float sc = sc8 / gscale;  // fp32 op order as reference
#pragma unroll
      for (int j = 0; j < 16; ++j) {
        float q = round_tiny(vals[j] / sc, 1, 0, 6.0f);  // fp4-e2m1 (true div: required)
        float d = q * sc8;                               // exact in bf16
        unsigned u = __float_as_uint(d);
        u += 0x7FFFu + ((u >> 16) & 1u);
        o[j] = (unsigned short)(u >> 16);
      }
    } else {
#pragma unroll
      for (int j = 0; j < 16; ++j) o[j] = 0;
    }
    uint4* dq = (uint4*)(dst + (size_t)i * 16);
    const uint4* oq = (const uint4*)o;
    dq[0] = oq[0];
    dq[1] = oq[1];
  }
}

// ---- 256x256 8-phase GEMM (T1+T2+T3+T4+T5), plain HIP per m201 template ----
// 8 waves (2M x 4N), per-wave C = 128x64 (8x4 frags). BK=64 = 2 K-halves.
// LDS ring: {A,B} x {buf0,buf1} x {khalf0,1} = 8 half-slots of 16 KiB (128 KiB).
// Stage stream: 1 half per phase, 5 halves ahead; counted vmcnt(2) at tile
// boundaries only (vmcnt(0) only for the last tile). Slot reuse distance = 8
// halves; stage-issue trails the slot's last read by 3 barrier-separated
// phases -> race-free. LDS layout: 2 rows per 128B + XOR of 16B-block with
// (row>>1)&3 -> max 2-way bank aliasing on ds_read_b128 (free, m136).
__global__ __launch_bounds__(512, 2) void gemm256(
    const unsigned short* __restrict__ A,   // [GM][GK] bf16 bits
    const unsigned short* __restrict__ Bt,  // [GN][GK] bf16 bits
    const float* __restrict__ bias,
    const unsigned int* __restrict__ amax2,
    float* __restrict__ C) {
  __shared__ char lds[131072];
  char* As = lds;
  char* Bs = lds + 65536;
  const int tid = threadIdx.x;
  const int lane = tid & 63;
  const int wave = tid >> 6;

  // T1: XCD swizzle (nwg=512, %8==0 -> simple form bijective)
  const int nwg = gridDim.x * gridDim.y;
  int id = blockIdx.y * gridDim.x + blockIdx.x;
  int swz = (id & 7) * (nwg >> 3) + (id >> 3);
  const int brow = (swz / gridDim.x) * BM;
  const int bcol = (swz % gridDim.x) * BN;

  const int wr = (wave >> 2) * 128;  // 0 or 128
  const int wc = (wave & 3) * 64;

  f32x4 acc[8][4] = {};

  // Staging precompute: chunk j covers LDS bytes [(j*8+wave)*1024, +1024).
  // Linear L -> logical (row, 16B-block): row=((L>>7)<<1)|((L>>6)&1),
  // cb_data=((L>>4)&3)^((L>>7)&3). Global source pre-swizzled accordingly.
  int ldsb[2], gA[2], gB[2];
#pragma unroll
  for (int j = 0; j < 2; ++j) {
    int L0 = (j * 8 + wave) * 1024;
    int L = L0 + lane * 16;
    int row = ((L >> 7) << 1) | ((L >> 6) & 1);
    int cb = ((L >> 4) & 3) ^ ((L >> 7) & 3);
    ldsb[j] = L0;                          // wave-uniform LDS base
    gA[j] = (brow + row) * GK + cb * 8;    // element offsets (k-tile added later)
    gB[j] = (bcol + row) * GK + cb * 8;
  }

  // Frag-read offsets within a 16 KiB half-slot (256 rows x 32 k bf16):
  // off = (row>>1)*128 + (row&1)*64 + ((cb ^ ((row>>1)&3))<<4), cb = lane>>4.
  int offA[8], offB[4];
#pragma unroll
  for (int m = 0; m < 8; ++m) {
    int row = wr + m * 16 + (lane & 15);
    offA[m] = ((row >> 1) << 7) + ((row & 1) << 6) + ((((lane >> 4) & 3) ^ ((row >> 1) & 3)) << 4);
  }
#pragma unroll
  for (int n = 0; n < 4; ++n) {
    int row = wc + n * 16 + (lane & 15);
    offB[n] = ((row >> 1) << 7) + ((row & 1) << 6) + ((((lane >> 4) & 3) ^ ((row >> 1) & 3)) << 4);
  }

  auto stage = [&](int s) {  // stage half-slot s of the stream
    if (s >= 4 * NT) return;
    int tau = s >> 2, r = s & 3;  // r: 0=A-k0 1=B-k0 2=A-k1 3=B-k1
    int kh = r >> 1;
    int kt = tau * BK + kh * 32;
    char* slot = ((r & 1) ? Bs : As) + ((((tau & 1) << 1) + kh) << 14);
    const unsigned short* op = (r & 1) ? Bt : A;
    const int* g = (r & 1) ? gB : gA;
#pragma unroll
    for (int j = 0; j < 2; ++j) {
      const unsigned short* src = op + (size_t)(g[j] + kt);
      __builtin_amdgcn_global_load_lds(
          (__attribute__((address_space(1))) void*)src,
          (__attribute__((address_space(3))) void*)(slot + ldsb[j]),
          16, 0, 0);
    }
  };

  // Prologue: issue 5 halves (tile 0 fully + 1 ahead).
  for (int s = 0; s < 5; ++s) stage(s);

  for (int t = 0; t < NT; ++t) {
    // Tile boundary: own loads for this tile landed; union over waves via barrier.
    if (t == NT - 1)
      asm volatile("s_waitcnt vmcnt(0)" ::: "memory");
    else
      asm volatile("s_waitcnt vmcnt(2)" ::: "memory");
    asm volatile("s_barrier" ::: "memory");

    char* At0 = As + (((t & 1) << 1) << 14);
    char* Bt0 = Bs + (((t & 1) << 1) << 14);
#pragma unroll
    for (int ksub = 0; ksub < 2; ++ksub) {
      const char* Aslot = At0 + (ksub << 14);
      const char* Bslot = Bt0 + (ksub << 14);
      bf16x8 a[8], b0, b1;
      // phase even: A frags (ksub) + B frags n0,n1
#pragma unroll
      for (int m = 0; m < 8; ++m) a[m] = *(const bf16x8*)(Aslot + offA[m]);
      b0 = *(const bf16x8*)(Bslot + offB[0]);
      b1 = *(const bf16x8*)(Bslot + offB[1]);
      stage(4 * t + ksub * 2 + 5);
      asm volatile("s_barrier" ::: "memory");
      asm volatile("s_waitcnt lgkmcnt(0)" ::: "memory");
      __builtin_amdgcn_sched_barrier(0);
      __builtin_amdgcn_s_setprio(1);
#pragma unroll
      for (int m = 0; m < 8; ++m) {
        acc[m][0] = __builtin_amdgcn_mfma_f32_16x16x32_bf16(a[m], b0, acc[m][0], 0, 0, 0);
        acc[m][1] = __builtin_amdgcn_mfma_f32_16x16x32_bf16(a[m], b1, acc[m][1], 0, 0, 0);
      }
      __builtin_amdgcn_s_setprio(0);
      asm volatile("s_barrier" ::: "memory");
      // phase odd: B frags n2,n3 (A reused from regs)
      b0 = *(const bf16x8*)(Bslot + offB[2]);
      b1 = *(const bf16x8*)(Bslot + offB[3]);
      stage(4 * t + ksub * 2 + 6);
      asm volatile("s_barrier" ::: "memory");
      asm volatile("s_waitcnt lgkmcnt(0)" ::: "memory");
      __builtin_amdgcn_sched_barrier(0);
      __builtin_amdgcn_s_setprio(1);
#pragma unroll
      for (int m = 0; m < 8; ++m) {
        acc[m][2] = __builtin_amdgcn_mfma_f32_16x16x32_bf16(a[m], b0, acc[m][2], 0, 0, 0);
        acc[m][3] = __builtin_amdgcn_mfma_f32_16x16x32_bf16(a[m], b1, acc[m][3], 0, 0, 0);
      }
      __builtin_amdgcn_s_setprio(0);
      asm volatile("s_barrier" ::: "memory");
    }
  }

  // Epilogue: C = acc/(gsx*gsw) + bias. C/D: col=lane&15, row=(lane>>4)*4+j.
  const float ax = __uint_as_float(amax2[0]);
  const float aw = __uint_as_float(amax2[1]);
  const float inv = 1.0f / ((2688.0f / ax) * (2688.0f / aw));
#pragma unroll
  for (int m = 0; m < 8; ++m) {
    int row0 = brow + wr + m * 16 + ((lane >> 4) << 2);
#pragma unroll
    for (int n = 0; n < 4; ++n) {
      int col = bcol + wc + n * 16 + (lane & 15);
      float bb = bias[col];
#pragma unroll
      for (int j = 0; j < 4; ++j)
        C[(size_t)(row0 + j) * GN + col] = acc[m][n][j] * inv + bb;
    }
  }
}

extern "C" void kernel_launch(void* const* d_in, const int* in_sizes, int n_in,
                              void* d_out, int out_size, void* d_ws, size_t ws_size,
                              hipStream_t stream) {
  const float* x = (const float*)d_in[0];
  const float* W = (const float*)d_in[1];
  const float* b = (const float*)d_in[2];
  float* out = (float*)d_out;

  // ws: [0,8) amax bits | +256: 1024 x-partials | +8192: 512 W-partials
  //     | +64KiB: A' bf16 (64 MiB) | B' bf16 (32 MiB). Total ~100.7 MB.
  unsigned int* amax2 = (unsigned int*)d_ws;
  float* px = (float*)((char*)d_ws + 256);
  float* pw = (float*)((char*)d_ws + 8192);
  unsigned short* Aq = (unsigned short*)((char*)d_ws + 65536);
  unsigned short* Bq = Aq + (size_t)GM * GK;

  amax_part<<<1024, 256, 0, stream>>>((const float4*)x, GM * GK / 4, px);
  amax_part<<<512, 256, 0, stream>>>((const float4*)W, GN * GK / 4, pw);
  amax_final<<<1, 512, 0, stream>>>(px, pw, amax2);
  quant_kernel<<<2048, 256, 0, stream>>>(x, Aq, amax2, GM * GK / 16);
  quant_kernel<<<2048, 256, 0, stream>>>(W, Bq, amax2 + 1, GN * GK / 16);
  dim3 grid(GN / BN, GM / BM);
  gemm256<<<grid, 512, 0, stream>>>(Aq, Bq, b, amax2, out);
}

// Round 7
// 528.305 us; speedup vs baseline: 1.6490x; 1.0024x over previous
//
#include <hip/hip_runtime.h>
#include <hip/hip_bf16.h>
#include <stdint.h>

// out[b,s,n] = sum_k nvfp4_fq(x)[b,s,k] * nvfp4_fq(W)[n,k] + bias[n]
// M=8192, N=4096, K=4096.
// Exactness: xq = q4*(sc8/gscale); q4 (e2m1) <=2-bit significand, sc8 (e4m3)
// <=4-bit -> product <=6-bit significand -> EXACT bf16. GEMM in bf16 MFMA
// (fp32 accum) == reference fp32 math modulo summation order; one deferred
// global scale 1/(gsx*gsw) in the epilogue.

#define GM 8192
#define GN 4096
#define GK 4096

#define BM 256
#define BN 256
#define BK 64
#define NT (GK / BK)

typedef short bf16x8 __attribute__((ext_vector_type(8)));
typedef float f32x4 __attribute__((ext_vector_type(4)));

// Reference _round_to_fp, bit-exact (pow2 mul replaces div-by-pow2: exact).
__device__ __forceinline__ float round_tiny(float x, int mant_bits, int min_exp, float max_val) {
  float a = fabsf(x);
  if (a == 0.0f) return 0.0f;
  int e = (int)((__float_as_uint(a) >> 23) & 0xFFu) - 127;
  if (e < min_exp) e = min_exp;
  float s_up = __int_as_float((unsigned)(mant_bits - e + 127) << 23);  // 2^(m-e)
  float s_dn = __int_as_float((unsigned)(e - mant_bits + 127) << 23);  // 2^(e-m)
  float q = fminf(rintf(a * s_up) * s_dn, max_val);
  return copysignf(q, x);
}

__device__ __forceinline__ unsigned short pack_bf16(float d) {  // RNE; exact for our d
  unsigned u = __float_as_uint(d);
  u += 0x7FFFu + ((u >> 16) & 1u);
  return (unsigned short)(u >> 16);
}

// K1: fused amax partials. Blocks [0,1024) stream x, [1024,1536) stream W.
__global__ void amax_part2(const float4* __restrict__ x4, int nx4,
                           const float4* __restrict__ w4, int nw4,
                           float* __restrict__ px, float* __restrict__ pw) {
  const int b = blockIdx.x;
  const bool isX = b < 1024;
  const float4* src = isX ? x4 : w4;
  const int n4 = isX ? nx4 : nw4;
  const int bb = isX ? b : b - 1024;
  const int nb = isX ? 1024 : 512;
  float m = 0.0f;
  const int stride = nb * 256;
  for (int i = bb * 256 + threadIdx.x; i < n4; i += stride) {
    float4 v = src[i];
    m = fmaxf(m, fmaxf(fmaxf(fabsf(v.x), fabsf(v.y)), fmaxf(fabsf(v.z), fabsf(v.w))));
  }
#pragma unroll
  for (int off = 32; off > 0; off >>= 1) m = fmaxf(m, __shfl_xor(m, off, 64));
  __shared__ float sm[4];
  if ((threadIdx.x & 63) == 0) sm[threadIdx.x >> 6] = m;
  __syncthreads();
  if (threadIdx.x == 0)
    (isX ? px : pw)[bb] = fmaxf(fmaxf(sm[0], sm[1]), fmaxf(sm[2], sm[3]));
}

// K2: fused quant. Blocks [0,2048) quant x -> Aq, [2048,3072) quant W -> Bq.
// Each block reduces the partial array itself (no separate final kernel);
// block 0 of each region publishes amax bits for the GEMM epilogue.
// 4 elems/lane + 2 shfl_xor for the 16-elem nvfp4 block max: coalesced
// 16 B/lane loads, 8 B/lane stores, no per-thread arrays.
__global__ void quant2(const float* __restrict__ x, const float* __restrict__ W,
                       const float* __restrict__ px, const float* __restrict__ pw,
                       unsigned short* __restrict__ Aq, unsigned short* __restrict__ Bq,
                       unsigned int* __restrict__ amax2) {
  const int tid = threadIdx.x;
  const bool isX = blockIdx.x < 2048;
  const float4* src = (const float4*)(isX ? x : W);
  ushort4* dst = (ushort4*)(isX ? Aq : Bq);
  const float* part = isX ? px : pw;
  const int pcnt = isX ? 1024 : 512;
  const int bb = isX ? blockIdx.x : blockIdx.x - 2048;
  const int nb = isX ? 2048 : 1024;
  const int n4 = isX ? (GM * GK / 4) : (GN * GK / 4);

  float m = 0.0f;
  for (int j = tid; j < pcnt; j += 256) m = fmaxf(m, part[j]);
#pragma unroll
  for (int off = 32; off > 0; off >>= 1) m = fmaxf(m, __shfl_xor(m, off, 64));
  __shared__ float sm[4];
  if ((tid & 63) == 0) sm[tid >> 6] = m;
  __syncthreads();
  const float amax = fmaxf(fmaxf(sm[0], sm[1]), fmaxf(sm[2], sm[3]));
  if (bb == 0 && tid == 0) amax2[isX ? 0 : 1] = __float_as_uint(amax);

  const float gscale = 2688.0f / amax;  // 448*6/amax, reference op order
  const int stride = nb * 256;
  // n4 / stride = 16 exactly for both regions -> uniform iteration count,
  // 4-lane shfl groups never diverge; groups are 4-aligned in f4 index.
  for (int i = bb * 256 + tid; i < n4; i += stride) {
    float4 v = src[i];
    float a = fmaxf(fmaxf(fabsf(v.x), fabsf(v.y)), fmaxf(fabsf(v.z), fabsf(v.w)));
    a = fmaxf(a, __shfl_xor(a, 1, 64));
    a = fmaxf(a, __shfl_xor(a, 2, 64));          // bmax of 16-elem nvfp4 block
    float sc8 = round_tiny(a / 6.0f * gscale, 3, -6, 448.0f);  // fp8-e4m3 scale
    ushort4 o;
    if (sc8 > 0.0f) {
      float sc = sc8 / gscale;                   // reference's sc (fp32 div)
      o.x = pack_bf16(round_tiny(v.x / sc, 1, 0, 6.0f) * sc8);
      o.y = pack_bf16(round_tiny(v.y / sc, 1, 0, 6.0f) * sc8);
      o.z = pack_bf16(round_tiny(v.z / sc, 1, 0, 6.0f) * sc8);
      o.w = pack_bf16(round_tiny(v.w / sc, 1, 0, 6.0f) * sc8);
    } else {
      o.x = o.y = o.z = o.w = 0;
    }
    dst[i] = o;
  }
}

// ---- 256x256 8-phase GEMM (T1+T2+T3+T4+T5) — FROZEN (passed r3: 255 us) ----
__global__ __launch_bounds__(512, 2) void gemm256(
    const unsigned short* __restrict__ A,   // [GM][GK] bf16 bits
    const unsigned short* __restrict__ Bt,  // [GN][GK] bf16 bits
    const float* __restrict__ bias,
    const unsigned int* __restrict__ amax2,
    float* __restrict__ C) {
  __shared__ char lds[131072];
  char* As = lds;
  char* Bs = lds + 65536;
  const int tid = threadIdx.x;
  const int lane = tid & 63;
  const int wave = tid >> 6;

  const int nwg = gridDim.x * gridDim.y;  // 512, %8==0 -> simple swizzle bijective
  int id = blockIdx.y * gridDim.x + blockIdx.x;
  int swz = (id & 7) * (nwg >> 3) + (id >> 3);
  const int brow = (swz / gridDim.x) * BM;
  const int bcol = (swz % gridDim.x) * BN;

  const int wr = (wave >> 2) * 128;
  const int wc = (wave & 3) * 64;

  f32x4 acc[8][4] = {};

  int ldsb[2], gA[2], gB[2];
#pragma unroll
  for (int j = 0; j < 2; ++j) {
    int L0 = (j * 8 + wave) * 1024;
    int L = L0 + lane * 16;
    int row = ((L >> 7) << 1) | ((L >> 6) & 1);
    int cb = ((L >> 4) & 3) ^ ((L >> 7) & 3);
    ldsb[j] = L0;
    gA[j] = (brow + row) * GK + cb * 8;
    gB[j] = (bcol + row) * GK + cb * 8;
  }

  int offA[8], offB[4];
#pragma unroll
  for (int m = 0; m < 8; ++m) {
    int row = wr + m * 16 + (lane & 15);
    offA[m] = ((row >> 1) << 7) + ((row & 1) << 6) + ((((lane >> 4) & 3) ^ ((row >> 1) & 3)) << 4);
  }
#pragma unroll
  for (int n = 0; n < 4; ++n) {
    int row = wc + n * 16 + (lane & 15);
    offB[n] = ((row >> 1) << 7) + ((row & 1) << 6) + ((((lane >> 4) & 3) ^ ((row >> 1) & 3)) << 4);
  }

  auto stage = [&](int s) {
    if (s >= 4 * NT) return;
    int tau = s >> 2, r = s & 3;  // 0=A-k0 1=B-k0 2=A-k1 3=B-k1
    int kh = r >> 1;
    int kt = tau * BK + kh * 32;
    char* slot = ((r & 1) ? Bs : As) + ((((tau & 1) << 1) + kh) << 14);
    const unsigned short* op = (r & 1) ? Bt : A;
    const int* g = (r & 1) ? gB : gA;
#pragma unroll
    for (int j = 0; j < 2; ++j) {
      const unsigned short* src = op + (size_t)(g[j] + kt);
      __builtin_amdgcn_global_load_lds(
          (__attribute__((address_space(1))) void*)src,
          (__attribute__((address_space(3))) void*)(slot + ldsb[j]),
          16, 0, 0);
    }
  };

  for (int s = 0; s < 5; ++s) stage(s);

  for (int t = 0; t < NT; ++t) {
    if (t == NT - 1)
      asm volatile("s_waitcnt vmcnt(0)" ::: "memory");
    else
      asm volatile("s_waitcnt vmcnt(2)" ::: "memory");
    asm volatile("s_barrier" ::: "memory");

    char* At0 = As + (((t & 1) << 1) << 14);
    char* Bt0 = Bs + (((t & 1) << 1) << 14);
#pragma unroll
    for (int ksub = 0; ksub < 2; ++ksub) {
      const char* Aslot = At0 + (ksub << 14);
      const char* Bslot = Bt0 + (ksub << 14);
      bf16x8 a[8], b0, b1;
#pragma unroll
      for (int m = 0; m < 8; ++m) a[m] = *(const bf16x8*)(Aslot + offA[m]);
      b0 = *(const bf16x8*)(Bslot + offB[0]);
      b1 = *(const bf16x8*)(Bslot + offB[1]);
      stage(4 * t + ksub * 2 + 5);
      asm volatile("s_barrier" ::: "memory");
      asm volatile("s_waitcnt lgkmcnt(0)" ::: "memory");
      __builtin_amdgcn_sched_barrier(0);
      __builtin_amdgcn_s_setprio(1);
#pragma unroll
      for (int m = 0; m < 8; ++m) {
        acc[m][0] = __builtin_amdgcn_mfma_f32_16x16x32_bf16(a[m], b0, acc[m][0], 0, 0, 0);
        acc[m][1] = __builtin_amdgcn_mfma_f32_16x16x32_bf16(a[m], b1, acc[m][1], 0, 0, 0);
      }
      __builtin_amdgcn_s_setprio(0);
      asm volatile("s_barrier" ::: "memory");
      b0 = *(const bf16x8*)(Bslot + offB[2]);
      b1 = *(const bf16x8*)(Bslot + offB[3]);
      stage(4 * t + ksub * 2 + 6);
      asm volatile("s_barrier" ::: "memory");
      asm volatile("s_waitcnt lgkmcnt(0)" ::: "memory");
      __builtin_amdgcn_sched_barrier(0);
      __builtin_amdgcn_s_setprio(1);
#pragma unroll
      for (int m = 0; m < 8; ++m) {
        acc[m][2] = __builtin_amdgcn_mfma_f32_16x16x32_bf16(a[m], b0, acc[m][2], 0, 0, 0);
        acc[m][3] = __builtin_amdgcn_mfma_f32_16x16x32_bf16(a[m], b1, acc[m][3], 0, 0, 0);
      }
      __builtin_amdgcn_s_setprio(0);
      asm volatile("s_barrier" ::: "memory");
    }
  }

  const float ax = __uint_as_float(amax2[0]);
  const float aw = __uint_as_float(amax2[1]);
  const float inv = 1.0f / ((2688.0f / ax) * (2688.0f / aw));
#pragma unroll
  for (int m = 0; m < 8; ++m) {
    int row0 = brow + wr + m * 16 + ((lane >> 4) << 2);
#pragma unroll
    for (int n = 0; n < 4; ++n) {
      int col = bcol + wc + n * 16 + (lane & 15);
      float bb = bias[col];
#pragma unroll
      for (int j = 0; j < 4; ++j)
        C[(size_t)(row0 + j) * GN + col] = acc[m][n][j] * inv + bb;
    }
  }
}

extern "C" void kernel_launch(void* const* d_in, const int* in_sizes, int n_in,
                              void* d_out, int out_size, void* d_ws, size_t ws_size,
                              hipStream_t stream) {
  const float* x = (const float*)d_in[0];
  const float* W = (const float*)d_in[1];
  const float* b = (const float*)d_in[2];
  float* out = (float*)d_out;

  // ws: [0,8) amax bits | +256: 1024 x-partials | +8192: 512 W-partials
  //     | +64KiB: A' bf16 (64 MiB) | B' bf16 (32 MiB). Total ~100.7 MB.
  unsigned int* amax2 = (unsigned int*)d_ws;
  float* px = (float*)((char*)d_ws + 256);
  float* pw = (float*)((char*)d_ws + 8192);
  unsigned short* Aq = (unsigned short*)((char*)d_ws + 65536);
  unsigned short* Bq = Aq + (size_t)GM * GK;

  amax_part2<<<1536, 256, 0, stream>>>((const float4*)x, GM * GK / 4,
                                       (const float4*)W, GN * GK / 4, px, pw);
  quant2<<<3072, 256, 0, stream>>>(x, W, px, pw, Aq, Bq, amax2);
  dim3 grid(GN / BN, GM / BM);
  gemm256<<<grid, 512, 0, stream>>>(Aq, Bq, b, amax2, out);
}